// Round 10
// baseline (264.490 us; speedup 1.0000x reference)
//
#include <hip/hip_runtime.h>
#include <hip/hip_bf16.h>
#include <stdint.h>

// KQV_28956669510232: out = softmax((x@Wq)(x@Wk)^T / 32, axis=keys) @ (x@Wv)
// B=4, S=2048, D=1024, fp32 in/out. bf16 MFMA GEMMs, materialized scores.
//
// R14: gemm_qkv LDS trimmed 33792 -> 32768 B => 4 -> 5 blocks/CU (160KiB/32K).
//      The vT-transpose epilogue now runs in TWO n-half passes through a
//      [64][132] view living inside the 32KB As+Bs region (write stride
//      264B = 2-way banks, free; reads 2-way, free). Main loop, staging,
//      MFMA, and all arithmetic identical to R13. Counters to watch:
//      LDS_Block_Size 32768, Occupancy ~24%, dur ~67-70us (was 75.6).
// R13: merged gemm_qkv (qk cols + fused vT transpose) + XCD swizzle.
// R12: softmax dispatch eliminated (shifted no-max softmax: P=exp(v-8),
//      rsum atomics in scores epilogue, divide in PV epilogue).
//
// ws layout (~102 MB):
//   xb   bf16 [8192][1024]   @ 0         (16 MB)
//   wt   bf16 [3072][1024]   @ 16777216  (6 MB)   rows: q,k,v (W^T)
//   bc   f32  [3072]         @ 23068672
//   qk   bf16 [8192][2048]   @ 23080960  (32 MB)  cols: q(0-1023), k(1024-2047)
//   vT   bf16 [4][1024][2048]@ 56635392  (16 MB)
//   P    bf16 [4][2048][2048]@ 73412608  (32 MB)  unnormalized exp
//   rsum f32  [4][2048]      @ 106967040 (32 KB)  row sums of P

typedef unsigned short u16;
typedef __bf16 bf16x8 __attribute__((ext_vector_type(8)));
typedef float  f32x4  __attribute__((ext_vector_type(4)));
typedef float  f32x16 __attribute__((ext_vector_type(16)));
typedef u16    u16x4  __attribute__((ext_vector_type(4)));
typedef u16    u16x8  __attribute__((ext_vector_type(8)));

__device__ __forceinline__ u16 f2bf(float f) {
  union { float f; uint32_t u; } v; v.f = f;
  uint32_t r = v.u + 0x7fffu + ((v.u >> 16) & 1u);   // RNE
  return (u16)(r >> 16);
}
__device__ __forceinline__ float bf2f(u16 b) {
  union { uint32_t u; float f; } v; v.u = (uint32_t)b << 16; return v.f;
}

#define GLD_LDS16(gp, lp) __builtin_amdgcn_global_load_lds(                   \
    (const __attribute__((address_space(1))) void*)(gp),                      \
    (__attribute__((address_space(3))) void*)(lp), 16, 0, 0)

// ---------------- fused prep: conv_x | W transpose+conv | bias | rsum=0 ---

__global__ __launch_bounds__(256)
void prep_all(const float* __restrict__ x,
              const float* __restrict__ Wq, const float* __restrict__ Wk,
              const float* __restrict__ Wv,
              const float* __restrict__ bq, const float* __restrict__ bk,
              const float* __restrict__ bv,
              u16* __restrict__ xb, u16* __restrict__ wt,
              float* __restrict__ bc, float* __restrict__ rsum) {
  __shared__ float t[32][33];
  const int bid = blockIdx.x;
  if (bid < 4096) {
    int i = (bid * 256 + threadIdx.x) * 8;
    float4 v0 = *(const float4*)(x + i);
    float4 v1 = *(const float4*)(x + i + 4);
    u16x8 o;
    o[0] = f2bf(v0.x); o[1] = f2bf(v0.y); o[2] = f2bf(v0.z); o[3] = f2bf(v0.w);
    o[4] = f2bf(v1.x); o[5] = f2bf(v1.y); o[6] = f2bf(v1.z); o[7] = f2bf(v1.w);
    *(u16x8*)(xb + i) = o;
  } else if (bid < 4096 + 3072) {
    int b2 = bid - 4096;
    int z = b2 >> 10, rem = b2 & 1023;
    int e0 = (rem & 31) * 32, d0 = (rem >> 5) * 32;
    const float* W = z == 0 ? Wq : (z == 1 ? Wk : Wv);
    u16* dst = wt + (size_t)z * 1024 * 1024;
    int tx = threadIdx.x & 31, ty = threadIdx.x >> 5;
    #pragma unroll
    for (int i = 0; i < 4; ++i)
      t[ty + i * 8][tx] = W[(size_t)(d0 + ty + i * 8) * 1024 + e0 + tx];
    __syncthreads();
    #pragma unroll
    for (int i = 0; i < 4; ++i)
      dst[(size_t)(e0 + ty + i * 8) * 1024 + d0 + tx] =
          f2bf(t[tx][ty + i * 8]);
  } else if (bid < 7180) {
    int i = (bid - 7168) * 256 + threadIdx.x;
    if (i < 3072)
      bc[i] = (i < 1024) ? bq[i] : (i < 2048 ? bk[i - 1024] : bv[i - 2048]);
  } else {
    float4 z4 = {0.f, 0.f, 0.f, 0.f};
    int i = (bid - 7180) * 2048 + threadIdx.x * 8;
    *(float4*)(rsum + i) = z4;
    *(float4*)(rsum + i + 4) = z4;
  }
}

// ---------------- fused QKV projection (m97 128^2) -----------------------
// N=3072 in one dispatch. bx<16: qk columns -> qk bf16 (ldc 2048, +bias).
// bx>=16: V columns -> vT[b][e][s] via two-pass LDS transpose (+bias).
// Grid (24,64) = 1536 blocks, bijective XCD swizzle. LDS exactly 32768 B
// => 5 blocks/CU.

__global__ __launch_bounds__(256)
void gemm_qkv(const u16* __restrict__ A, int lda,
              const u16* __restrict__ B, int ldb,
              u16* __restrict__ C, int ldc,
              const float* __restrict__ bias, int K,
              u16* __restrict__ vTp) {
  __shared__ __align__(16) u16 smem[128 * 128];   // 32768 B exactly
  u16* As = smem;            // 128*64
  u16* Bs = smem + 8192;     // 128*64
  const int lane = threadIdx.x & 63;
  const int wv = threadIdx.x >> 6;

  // bijective XCD swizzle (nwg = 24*64 = 1536, % 8 == 0)
  const int flat = blockIdx.y * 24 + blockIdx.x;
  const int swz = (flat & 7) * 192 + (flat >> 3);
  const int bx = swz % 24, by = swz / 24;

  const u16* Ab = A + (size_t)by * 128 * lda;
  const u16* Bb = B + (size_t)bx * 128 * ldb;

  const int srow = lane >> 3;
  const int scol = ((lane & 7) ^ (lane >> 3)) * 8;
  const int r32 = lane & 31;
  const int half = lane >> 5;
  const int rx = lane & 7;
  const int wm = (wv >> 1) * 64;
  const int wn = (wv & 1) * 64;

  f32x16 acc[2][2];
  #pragma unroll
  for (int i = 0; i < 2; ++i)
    #pragma unroll
    for (int j = 0; j < 2; ++j) acc[i][j] = (f32x16)0.0f;

  for (int k0 = 0; k0 < K; k0 += 64) {
    #pragma unroll
    for (int i = 0; i < 4; ++i) {
      int r = wv * 32 + i * 8;  // wave-uniform
      GLD_LDS16(Ab + (size_t)(r + srow) * lda + k0 + scol, As + r * 64);
      GLD_LDS16(Bb + (size_t)(r + srow) * ldb + k0 + scol, Bs + r * 64);
    }
    __syncthreads();

    bf16x8 af[2][4], bfr[2][4];
    #pragma unroll
    for (int i = 0; i < 2; ++i)
      #pragma unroll
      for (int t = 0; t < 4; ++t) {
        int pc = ((t * 2 + half) ^ rx) * 8;
        af[i][t]  = *(const bf16x8*)(As + (wm + i * 32 + r32) * 64 + pc);
        bfr[i][t] = *(const bf16x8*)(Bs + (wn + i * 32 + r32) * 64 + pc);
      }
    #pragma unroll
    for (int i = 0; i < 2; ++i)
      #pragma unroll
      for (int j = 0; j < 2; ++j)
        #pragma unroll
        for (int t = 0; t < 4; ++t)
          acc[i][j] = __builtin_amdgcn_mfma_f32_32x32x16_bf16(
              af[i][t], bfr[j][t], acc[i][j], 0, 0, 0);
    __syncthreads();
  }

  // C/D layout (32x32): col = lane&31, row = (e&3) + 8*(e>>2) + 4*(lane>>5)
  if (bx < 16) {
    // q/k columns: bf16 C-write (+bias), packed qk buffer ldc=2048
    const int ccol0 = bx * 128 + wn + r32;
    const int crow0 = by * 128 + wm + 4 * half;
    #pragma unroll
    for (int i = 0; i < 2; ++i) {
      #pragma unroll
      for (int e = 0; e < 16; ++e) {
        int m = crow0 + i * 32 + (e & 3) + 8 * (e >> 2);
        #pragma unroll
        for (int j = 0; j < 2; ++j) {
          int n = ccol0 + j * 32;
          C[(size_t)m * ldc + n] = f2bf(acc[i][j][e] + bias[n]);
        }
      }
    }
  } else {
    // V columns: two-pass transpose through [64][132] LDS view
    u16 (*t)[132] = (u16(*)[132])smem;   // 64*132*2 = 16896 B <= 32768
    const int tid = threadIdx.x;
    const int bb = by >> 4;
    const int s0 = (by & 15) * 128 + (tid & 15) * 8;
    const int e_base = (bx - 16) * 128;
    u16* dstb = vTp + (size_t)bb * 1024 * 2048;
    #pragma unroll
    for (int nh = 0; nh < 2; ++nh) {
      __syncthreads();              // prior smem reads complete
      if ((wv & 1) == nh) {         // wave-uniform: this wave owns half nh
        #pragma unroll
        for (int i = 0; i < 2; ++i) {
          #pragma unroll
          for (int j = 0; j < 2; ++j) {
            const int nl = j * 32 + r32;            // local row within half
            const float bvv = bias[bx * 128 + wn + nl];
            #pragma unroll
            for (int eg = 0; eg < 4; ++eg) {
              const int mb = wm + i * 32 + 4 * half + 8 * eg;
              u16x4 o;
              #pragma unroll
              for (int q = 0; q < 4; ++q)
                o[q] = f2bf(acc[i][j][eg * 4 + q] + bvv);
              *(u16x4*)&t[nl][mb] = o;
            }
          }
        }
      }
      __syncthreads();
      #pragma unroll
      for (int p = 0; p < 4; ++p) {
        const int el = (tid >> 4) + p * 16;
        u16x8 o;
        #pragma unroll
        for (int q = 0; q < 8; ++q) o[q] = t[el][(tid & 15) * 8 + q];
        *(u16x8*)(dstb + (size_t)(e_base + nh * 64 + el) * 2048 + s0) = o;
      }
    }
  }
}

// ---------------- 8-phase 256x256 scores GEMM + fused exp/rowsum ----------
// P[m][n] = bf16(exp(scale*sum_k q[m][k]*k[n][k] - 8)); rsum[m] += row sums
// of the ROUNDED values. Structure identical to the R8-verified gemm8p.

#define FENCE8 asm volatile("" ::: "memory")
#define BARR8  do { FENCE8; __builtin_amdgcn_s_barrier(); FENCE8; } while (0)
#define WAITL8 asm volatile("s_waitcnt lgkmcnt(0)" ::: "memory")
#define VMW(N) asm volatile("s_waitcnt vmcnt(" #N ")" ::: "memory")

#define STAGE_A8(S, H, TT) do {                                               \
    GLD_LDS16(pA[H][0] + (TT) * 64,                                           \
              As + (S) * 16384 + ((H) * 64 + wv * 8) * 64);                   \
    GLD_LDS16(pA[H][1] + (TT) * 64,                                           \
              As + (S) * 16384 + ((H) * 64 + 128 + wv * 8) * 64);             \
  } while (0)

#define STAGE_B8(S, H, TT) do {                                               \
    GLD_LDS16(pB[H][0] + (TT) * 64,                                           \
              Bs + (S) * 16384 + ((H) * 32 + (wv >> 2) * 64 + (wv & 3) * 8) * 64); \
    GLD_LDS16(pB[H][1] + (TT) * 64,                                           \
              Bs + (S) * 16384 + ((H) * 32 + 128 + (wv >> 2) * 64 + (wv & 3) * 8) * 64); \
  } while (0)

#define RD_A8(S, MH) do {                                                     \
    _Pragma("unroll")                                                         \
    for (int mf = 0; mf < 4; ++mf) {                                          \
      const u16* p_ = As + (S) * 16384 + rdA + ((MH) * 64 + mf * 16) * 64;    \
      a[mf][0] = *(const bf16x8*)(p_ + pos0);                                 \
      a[mf][1] = *(const bf16x8*)(p_ + pos1);                                 \
    }                                                                         \
  } while (0)

#define RD_B8(S, NH) do {                                                     \
    _Pragma("unroll")                                                         \
    for (int nf = 0; nf < 2; ++nf) {                                          \
      const u16* p_ = Bs + (S) * 16384 + rdB + ((NH) * 32 + nf * 16) * 64;    \
      b[nf][0] = *(const bf16x8*)(p_ + pos0);                                 \
      b[nf][1] = *(const bf16x8*)(p_ + pos1);                                 \
    }                                                                         \
  } while (0)

#define MFMA_Q8(MH, NH) do {                                                  \
    _Pragma("unroll")                                                         \
    for (int ks = 0; ks < 2; ++ks)                                            \
      _Pragma("unroll")                                                       \
      for (int mf = 0; mf < 4; ++mf)                                          \
        _Pragma("unroll")                                                     \
        for (int nf = 0; nf < 2; ++nf)                                        \
          acc[(MH) * 4 + mf][(NH) * 2 + nf] =                                 \
              __builtin_amdgcn_mfma_f32_16x16x32_bf16(                        \
                  a[mf][ks], b[nf][ks], acc[(MH) * 4 + mf][(NH) * 2 + nf],    \
                  0, 0, 0);                                                   \
  } while (0)

#define GROUP8(S, T, EN1, EN2, WAITST) do {                                   \
    RD_A8(S, 0); RD_B8(S, 0);                                                 \
    if (EN1) STAGE_B8((S) ^ 1, 0, (T) + 1);                                   \
    BARR8; WAITL8;                                                            \
    __builtin_amdgcn_s_setprio(1); MFMA_Q8(0, 0);                             \
    __builtin_amdgcn_s_setprio(0); BARR8;                                     \
    RD_B8(S, 1);                                                              \
    if (EN2) STAGE_A8(S, 0, (T) + 2);                                         \
    BARR8; WAITL8;                                                            \
    __builtin_amdgcn_s_setprio(1); MFMA_Q8(0, 1);                             \
    __builtin_amdgcn_s_setprio(0); BARR8;                                     \
    RD_A8(S, 1);                                                              \
    if (EN2) STAGE_B8(S, 1, (T) + 2);                                         \
    BARR8; WAITL8;                                                            \
    __builtin_amdgcn_s_setprio(1); MFMA_Q8(1, 1);                             \
    __builtin_amdgcn_s_setprio(0); BARR8;                                     \
    RD_B8(S, 0);                                                              \
    if (EN2) STAGE_A8(S, 1, (T) + 2);                                         \
    BARR8; WAITL8;                                                            \
    __builtin_amdgcn_s_setprio(1); MFMA_Q8(1, 0);                             \
    __builtin_amdgcn_s_setprio(0); WAITST; BARR8;                             \
  } while (0)

template <int NT>
__global__ __launch_bounds__(512)
void gemm8s(const u16* __restrict__ A, int lda, long long sA,
            const u16* __restrict__ B, int ldb, long long sB,
            u16* __restrict__ C, int ldc, long long sC,
            float* __restrict__ rsum, float scale) {
  __shared__ __align__(16) u16 As[2 * 256 * 64];
  __shared__ __align__(16) u16 Bs[2 * 256 * 64];

  const int lane = threadIdx.x & 63;
  const int wv   = threadIdx.x >> 6;    // 0..7
  const int wm   = wv >> 2;             // 0..1
  const int wn   = wv & 3;              // 0..3
  const int l15  = lane & 15;
  const int hi4  = lane >> 4;           // 0..3
  const int rx7  = lane & 7;
  const int srow = lane >> 3;           // 0..7
  const int scem = ((lane & 7) ^ srow) * 8;

  // bijective XCD swizzle (nwg % 8 == 0)
  const int nx = gridDim.x;
  const int flat = blockIdx.y * nx + blockIdx.x;
  const int nwg = nx * gridDim.y;
  const int cpx = nwg >> 3;
  const int swz = (flat & 7) * cpx + (flat >> 3);
  const int bx = swz % nx, by = swz / nx;

  const u16* Ab = A + (size_t)blockIdx.z * sA + (size_t)by * 256 * lda;
  const u16* Bb = B + (size_t)blockIdx.z * sB + (size_t)bx * 256 * ldb;

  const u16* pA[2][2];
  const u16* pB[2][2];
  #pragma unroll
  for (int h = 0; h < 2; ++h)
    #pragma unroll
    for (int r = 0; r < 2; ++r) {
      pA[h][r] = Ab + (size_t)(h * 64 + r * 128 + wv * 8 + srow) * lda + scem;
      pB[h][r] = Bb + (size_t)(h * 32 + r * 128 + (wv >> 2) * 64 +
                               (wv & 3) * 8 + srow) * ldb + scem;
    }

  const int rdA = (wm * 128 + l15) * 64;
  const int rdB = (wn * 64 + l15) * 64;
  const int pos0 = (hi4 ^ rx7) * 8;
  const int pos1 = ((4 + hi4) ^ rx7) * 8;

  f32x4 acc[8][4];
  #pragma unroll
  for (int i = 0; i < 8; ++i)
    #pragma unroll
    for (int j = 0; j < 4; ++j) acc[i][j] = (f32x4)0.0f;

  bf16x8 a[4][2], b[2][2];

  STAGE_A8(0, 0, 0); STAGE_B8(0, 1, 0); STAGE_A8(0, 1, 0); STAGE_B8(0, 0, 0);
  VMW(4);
  STAGE_A8(1, 0, 1); STAGE_B8(1, 1, 1); STAGE_A8(1, 1, 1);
  VMW(6);
  BARR8;

  #pragma unroll 1
  for (int i = 0; i < NT / 2 - 1; ++i) {
    const int t0 = 2 * i;
    GROUP8(0, t0,     1, 1, VMW(6));
    GROUP8(1, t0 + 1, 1, 1, VMW(6));
  }
  GROUP8(0, NT - 2, 1, 0, VMW(0));
  GROUP8(1, NT - 1, 0, 0, (void)0);

  // epilogue: P = bf16(exp(v-8)), rsum[m] += sum of rounded row values
  const int m0 = by * 256 + wm * 128;
  const int n0 = bx * 256 + wn * 64;
  u16* Cb = C + (size_t)blockIdx.z * sC;
  float* rsz = rsum + blockIdx.z * 2048;
  #pragma unroll
  for (int fm = 0; fm < 8; ++fm) {
    const int mb = m0 + (fm >> 2) * 64 + (fm & 3) * 16 + hi4 * 4;
    #pragma unroll
    for (int e = 0; e < 4; ++e) {
      const int m = mb + e;
      float local = 0.f;
      #pragma unroll
      for (int fn = 0; fn < 4; ++fn) {
        const int n = n0 + (fn >> 1) * 32 + (fn & 1) * 16 + l15;
        float ex = exp2f((acc[fm][fn][e] * scale - 8.0f) * 1.44269504f);
        u16 pb = f2bf(ex);
        Cb[(size_t)m * ldc + n] = pb;
        local += bf2f(pb);
      }
      #pragma unroll
      for (int mk = 1; mk < 16; mk <<= 1) local += __shfl_xor(local, mk);
      if (l15 == 0) atomicAdd(&rsz[m], local);
    }
  }
}

// ---------------- PV GEMM: m97-style 512-thread, normalize by rsum --------
// out[m][n] = (sum_k P[m][k]*vT[n][k]) / rsum[m]. Grid (8,16,4) = 512 blocks.

__global__ __launch_bounds__(512)
void gemm_bt8(const u16* __restrict__ A, int lda, long long sA,
              const u16* __restrict__ B, int ldb, long long sB,
              float* __restrict__ C, int ldc, long long sC,
              int K, const float* __restrict__ rsum) {
  __shared__ u16 As[128 * 64];
  __shared__ u16 Bs[128 * 64];
  const int lane = threadIdx.x & 63;
  const int wv = threadIdx.x >> 6;          // 0..7

  const u16* Ab = A + (size_t)blockIdx.z * sA + (size_t)blockIdx.y * 128 * lda;
  const u16* Bb = B + (size_t)blockIdx.z * sB + (size_t)blockIdx.x * 128 * ldb;

  const int srow = lane >> 3;
  const int scol = ((lane & 7) ^ (lane >> 3)) * 8;
  const int r32 = lane & 31;
  const int half = lane >> 5;
  const int rx = lane & 7;
  const int wm = (wv >> 2) * 64;
  const int wn = (wv & 3) * 32;

  f32x16 acc[2];
  acc[0] = (f32x16)0.0f; acc[1] = (f32x16)0.0f;

  for (int k0 = 0; k0 < K; k0 += 64) {
    #pragma unroll
    for (int i = 0; i < 2; ++i) {
      int r = wv * 16 + i * 8;
      GLD_LDS16(Ab + (size_t)(r + srow) * lda + k0 + scol, As + r * 64);
      GLD_LDS16(Bb + (size_t)(r + srow) * ldb + k0 + scol, Bs + r * 64);
    }
    __syncthreads();

    bf16x8 af[2][4], bfr[4];
    #pragma unroll
    for (int t = 0; t < 4; ++t) {
      int pc = ((t * 2 + half) ^ rx) * 8;
      af[0][t] = *(const bf16x8*)(As + (wm + r32) * 64 + pc);
      af[1][t] = *(const bf16x8*)(As + (wm + 32 + r32) * 64 + pc);
      bfr[t]   = *(const bf16x8*)(Bs + (wn + r32) * 64 + pc);
    }
    #pragma unroll
    for (int i = 0; i < 2; ++i)
      #pragma unroll
      for (int t = 0; t < 4; ++t)
        acc[i] = __builtin_amdgcn_mfma_f32_32x32x16_bf16(
            af[i][t], bfr[t], acc[i], 0, 0, 0);
    __syncthreads();
  }

  const int ccol = blockIdx.x * 128 + wn + r32;
  const int crow0 = blockIdx.y * 128 + wm + 4 * half;
  float* Cf = C + (size_t)blockIdx.z * sC;
  const float* rsz = rsum + blockIdx.z * 2048;
  #pragma unroll
  for (int i = 0; i < 2; ++i)
    #pragma unroll
    for (int e = 0; e < 16; ++e) {
      int m = crow0 + i * 32 + (e & 3) + 8 * (e >> 2);
      Cf[(size_t)m * ldc + ccol] = acc[i][e] / rsz[m];
    }
}

// ---------------- launch ----------------

extern "C" void kernel_launch(void* const* d_in, const int* in_sizes, int n_in,
                              void* d_out, int out_size, void* d_ws, size_t ws_size,
                              hipStream_t stream) {
  const float* x  = (const float*)d_in[0];
  const float* Wk = (const float*)d_in[1];
  const float* bk = (const float*)d_in[2];
  const float* Wq = (const float*)d_in[3];
  const float* bq = (const float*)d_in[4];
  const float* Wv = (const float*)d_in[5];
  const float* bv = (const float*)d_in[6];
  float* out = (float*)d_out;

  char* ws = (char*)d_ws;
  u16*   xb   = (u16*)(ws + 0);
  u16*   wt   = (u16*)(ws + 16777216);
  float* bc   = (float*)(ws + 23068672);
  u16*   qk   = (u16*)(ws + 23080960);
  u16*   vT   = (u16*)(ws + 56635392);
  u16*   P    = (u16*)(ws + 73412608);
  float* rsum = (float*)(ws + 106967040);
  (void)in_sizes; (void)n_in; (void)out_size; (void)ws_size;

  // 1. fused prep: x->bf16 | W^T->bf16 | bias | rsum = 0
  prep_all<<<7184, 256, 0, stream>>>(x, Wq, Wk, Wv, bq, bk, bv, xb, wt, bc,
                                     rsum);

  // 2. fused QKV projection: q/k cols -> qk (ldc 2048), v cols -> vT
  //    (m97 128^2, grid 24x64 = 1536 blocks, XCD swizzled, 5 blocks/CU)
  gemm_qkv<<<dim3(24, 64, 1), 256, 0, stream>>>(
      xb, 1024, wt, 1024, qk, 2048, bc, 1024, vT);

  // 3. scores -> P = exp(qk^T/32 - 8) bf16, rsum accumulated (8-phase 256^2)
  gemm8s<16><<<dim3(8, 8, 4), 512, 0, stream>>>(
      qk, 2048, 2048LL * 2048, qk + 1024, 2048, 2048LL * 2048,
      P, 2048, 2048LL * 2048, rsum, 0.03125f);

  // 4. out = (P @ V) / rsum  (m97-style 512-thread, 512 blocks)
  gemm_bt8<<<dim3(8, 16, 4), 512, 0, stream>>>(
      P, 2048, 2048LL * 2048, vT, 2048, 1024LL * 2048,
      out, 1024, 2048LL * 1024, 2048, rsum);
}

// Round 11
// 252.592 us; speedup vs baseline: 1.0471x; 1.0471x over previous
//
#include <hip/hip_runtime.h>
#include <hip/hip_bf16.h>
#include <stdint.h>

// KQV_28956669510232: out = softmax((x@Wq)(x@Wk)^T / 32, axis=keys) @ (x@Wv)
// B=4, S=2048, D=1024, fp32 in/out. bf16 MFMA GEMMs, materialized scores.
//
// R15: revert to R13 config (best passing 261.98us; R14's 32KB two-pass
//      epilogue was neutral-to-worse: occupancy unchanged 19.3%, dur +1.6us
//      -> m97 structure is schedule-bound, not LDS/occupancy-capped).
//      One change: prep_all W-transpose rebuilt on 64x64 tiles (768 blocks):
//      coalesced 256B f32 row loads into t[64][65], 128B-contiguous u16x8
//      stores (was 64B/row scalar stores). ~2x write efficiency on the
//      W-part of prep (~10 -> ~5us).
// R13: merged gemm_qkv (qk cols + fused vT transpose, 33792B LDS) + XCD swz.
// R12: softmax dispatch eliminated (P=exp(v-8), rsum atomics, divide in PV).
//
// ws layout (~102 MB):
//   xb   bf16 [8192][1024]   @ 0         (16 MB)
//   wt   bf16 [3072][1024]   @ 16777216  (6 MB)   rows: q,k,v (W^T)
//   bc   f32  [3072]         @ 23068672
//   qk   bf16 [8192][2048]   @ 23080960  (32 MB)  cols: q(0-1023), k(1024-2047)
//   vT   bf16 [4][1024][2048]@ 56635392  (16 MB)
//   P    bf16 [4][2048][2048]@ 73412608  (32 MB)  unnormalized exp
//   rsum f32  [4][2048]      @ 106967040 (32 KB)  row sums of P

typedef unsigned short u16;
typedef __bf16 bf16x8 __attribute__((ext_vector_type(8)));
typedef float  f32x4  __attribute__((ext_vector_type(4)));
typedef float  f32x16 __attribute__((ext_vector_type(16)));
typedef u16    u16x4  __attribute__((ext_vector_type(4)));
typedef u16    u16x8  __attribute__((ext_vector_type(8)));

__device__ __forceinline__ u16 f2bf(float f) {
  union { float f; uint32_t u; } v; v.f = f;
  uint32_t r = v.u + 0x7fffu + ((v.u >> 16) & 1u);   // RNE
  return (u16)(r >> 16);
}
__device__ __forceinline__ float bf2f(u16 b) {
  union { uint32_t u; float f; } v; v.u = (uint32_t)b << 16; return v.f;
}

#define GLD_LDS16(gp, lp) __builtin_amdgcn_global_load_lds(                   \
    (const __attribute__((address_space(1))) void*)(gp),                      \
    (__attribute__((address_space(3))) void*)(lp), 16, 0, 0)

// ---------------- fused prep: conv_x | W transpose+conv | bias | rsum=0 ---
// grid: 4096 (x-conv) + 768 (W 64x64 tiles) + 12 (bias) + 4 (rsum) = 4880

__global__ __launch_bounds__(256)
void prep_all(const float* __restrict__ x,
              const float* __restrict__ Wq, const float* __restrict__ Wk,
              const float* __restrict__ Wv,
              const float* __restrict__ bq, const float* __restrict__ bk,
              const float* __restrict__ bv,
              u16* __restrict__ xb, u16* __restrict__ wt,
              float* __restrict__ bc, float* __restrict__ rsum) {
  __shared__ float t[64][65];   // 16.6 KB
  const int bid = blockIdx.x;
  const int tid = threadIdx.x;
  if (bid < 4096) {
    int i = (bid * 256 + tid) * 8;
    float4 v0 = *(const float4*)(x + i);
    float4 v1 = *(const float4*)(x + i + 4);
    u16x8 o;
    o[0] = f2bf(v0.x); o[1] = f2bf(v0.y); o[2] = f2bf(v0.z); o[3] = f2bf(v0.w);
    o[4] = f2bf(v1.x); o[5] = f2bf(v1.y); o[6] = f2bf(v1.z); o[7] = f2bf(v1.w);
    *(u16x8*)(xb + i) = o;
  } else if (bid < 4096 + 768) {
    // W [1024][1024] f32 -> Wt bf16 with Wt[e][d] = W[d][e]; 64x64 tiles
    int b2 = bid - 4096;
    int z = b2 >> 8, rem = b2 & 255;
    int e0 = (rem & 15) * 64, d0 = (rem >> 4) * 64;
    const float* W = z == 0 ? Wq : (z == 1 ? Wk : Wv);
    u16* dst = wt + (size_t)z * 1024 * 1024;
    const int tx = tid & 63, ty = tid >> 6;          // tx: col, ty: 0..3
    #pragma unroll
    for (int i = 0; i < 16; ++i)
      t[ty + i * 4][tx] = W[(size_t)(d0 + ty + i * 4) * 1024 + e0 + tx];
    __syncthreads();
    const int er = tid >> 3, ec = (tid & 7) * 8;     // er: 0..31, ec: 0..56
    #pragma unroll
    for (int p = 0; p < 2; ++p) {
      const int row = er + p * 32;                   // e-row within tile
      u16x8 o;
      #pragma unroll
      for (int q = 0; q < 8; ++q) o[q] = f2bf(t[ec + q][row]);
      *(u16x8*)(dst + (size_t)(e0 + row) * 1024 + d0 + ec) = o;
    }
  } else if (bid < 4096 + 768 + 12) {
    int i = (bid - 4864) * 256 + tid;
    if (i < 3072)
      bc[i] = (i < 1024) ? bq[i] : (i < 2048 ? bk[i - 1024] : bv[i - 2048]);
  } else {
    float4 z4 = {0.f, 0.f, 0.f, 0.f};
    int i = (bid - 4876) * 2048 + tid * 8;
    *(float4*)(rsum + i) = z4;
    *(float4*)(rsum + i + 4) = z4;
  }
}

// ---------------- fused QKV projection (m97 128^2) -----------------------
// N=3072 in one dispatch. bx<16: qk columns -> qk bf16 (ldc 2048, +bias).
// bx>=16: V columns -> vT[b][e][s] via LDS transpose (+bias). Grid (24,64)
// = 1536 blocks, bijective XCD swizzle (1536 % 8 == 0).

__global__ __launch_bounds__(256)
void gemm_qkv(const u16* __restrict__ A, int lda,
              const u16* __restrict__ B, int ldb,
              u16* __restrict__ C, int ldc,
              const float* __restrict__ bias, int K,
              u16* __restrict__ vTp) {
  __shared__ __align__(16) u16 smem[128 * 132];   // 33792 B
  u16* As = smem;            // 128*64
  u16* Bs = smem + 8192;     // 128*64
  const int lane = threadIdx.x & 63;
  const int wv = threadIdx.x >> 6;

  // bijective XCD swizzle (nwg = 24*64 = 1536, % 8 == 0)
  const int flat = blockIdx.y * 24 + blockIdx.x;
  const int swz = (flat & 7) * 192 + (flat >> 3);
  const int bx = swz % 24, by = swz / 24;

  const u16* Ab = A + (size_t)by * 128 * lda;
  const u16* Bb = B + (size_t)bx * 128 * ldb;

  const int srow = lane >> 3;
  const int scol = ((lane & 7) ^ (lane >> 3)) * 8;
  const int r32 = lane & 31;
  const int half = lane >> 5;
  const int rx = lane & 7;
  const int wm = (wv >> 1) * 64;
  const int wn = (wv & 1) * 64;

  f32x16 acc[2][2];
  #pragma unroll
  for (int i = 0; i < 2; ++i)
    #pragma unroll
    for (int j = 0; j < 2; ++j) acc[i][j] = (f32x16)0.0f;

  for (int k0 = 0; k0 < K; k0 += 64) {
    #pragma unroll
    for (int i = 0; i < 4; ++i) {
      int r = wv * 32 + i * 8;  // wave-uniform
      GLD_LDS16(Ab + (size_t)(r + srow) * lda + k0 + scol, As + r * 64);
      GLD_LDS16(Bb + (size_t)(r + srow) * ldb + k0 + scol, Bs + r * 64);
    }
    __syncthreads();

    bf16x8 af[2][4], bfr[2][4];
    #pragma unroll
    for (int i = 0; i < 2; ++i)
      #pragma unroll
      for (int t = 0; t < 4; ++t) {
        int pc = ((t * 2 + half) ^ rx) * 8;
        af[i][t]  = *(const bf16x8*)(As + (wm + i * 32 + r32) * 64 + pc);
        bfr[i][t] = *(const bf16x8*)(Bs + (wn + i * 32 + r32) * 64 + pc);
      }
    #pragma unroll
    for (int i = 0; i < 2; ++i)
      #pragma unroll
      for (int j = 0; j < 2; ++j)
        #pragma unroll
        for (int t = 0; t < 4; ++t)
          acc[i][j] = __builtin_amdgcn_mfma_f32_32x32x16_bf16(
              af[i][t], bfr[j][t], acc[i][j], 0, 0, 0);
    __syncthreads();
  }

  // C/D layout (32x32): col = lane&31, row = (e&3) + 8*(e>>2) + 4*(lane>>5)
  if (bx < 16) {
    // q/k columns: bf16 C-write (+bias), packed qk buffer ldc=2048
    const int ccol0 = bx * 128 + wn + r32;
    const int crow0 = by * 128 + wm + 4 * half;
    #pragma unroll
    for (int i = 0; i < 2; ++i) {
      #pragma unroll
      for (int e = 0; e < 16; ++e) {
        int m = crow0 + i * 32 + (e & 3) + 8 * (e >> 2);
        #pragma unroll
        for (int j = 0; j < 2; ++j) {
          int n = ccol0 + j * 32;
          C[(size_t)m * ldc + n] = f2bf(acc[i][j][e] + bias[n]);
        }
      }
    }
  } else {
    // V columns: transpose through LDS, write vT[b][e][s]
    u16 (*t)[132] = (u16(*)[132])smem;   // [n_local][m_local], pad 132
    #pragma unroll
    for (int i = 0; i < 2; ++i) {
      #pragma unroll
      for (int j = 0; j < 2; ++j) {
        const int nl = wn + j * 32 + r32;
        const float bvv = bias[bx * 128 + nl];
        #pragma unroll
        for (int eg = 0; eg < 4; ++eg) {
          const int mb = wm + i * 32 + 4 * half + 8 * eg;
          u16x4 o;
          #pragma unroll
          for (int q = 0; q < 4; ++q) o[q] = f2bf(acc[i][j][eg * 4 + q] + bvv);
          *(u16x4*)&t[nl][mb] = o;
        }
      }
    }
    __syncthreads();
    const int tid = threadIdx.x;
    const int bb = by >> 4;
    const int s0 = (by & 15) * 128 + (tid & 15) * 8;
    const int e_base = (bx - 16) * 128;
    u16* dstb = vTp + (size_t)bb * 1024 * 2048;
    #pragma unroll
    for (int p = 0; p < 8; ++p) {
      const int el = (tid >> 4) + p * 16;
      u16x8 o;
      #pragma unroll
      for (int q = 0; q < 8; ++q) o[q] = t[el][(tid & 15) * 8 + q];
      *(u16x8*)(dstb + (size_t)(e_base + el) * 2048 + s0) = o;
    }
  }
}

// ---------------- 8-phase 256x256 scores GEMM + fused exp/rowsum ----------
// P[m][n] = bf16(exp(scale*sum_k q[m][k]*k[n][k] - 8)); rsum[m] += row sums
// of the ROUNDED values. Structure identical to the R8-verified gemm8p.

#define FENCE8 asm volatile("" ::: "memory")
#define BARR8  do { FENCE8; __builtin_amdgcn_s_barrier(); FENCE8; } while (0)
#define WAITL8 asm volatile("s_waitcnt lgkmcnt(0)" ::: "memory")
#define VMW(N) asm volatile("s_waitcnt vmcnt(" #N ")" ::: "memory")

#define STAGE_A8(S, H, TT) do {                                               \
    GLD_LDS16(pA[H][0] + (TT) * 64,                                           \
              As + (S) * 16384 + ((H) * 64 + wv * 8) * 64);                   \
    GLD_LDS16(pA[H][1] + (TT) * 64,                                           \
              As + (S) * 16384 + ((H) * 64 + 128 + wv * 8) * 64);             \
  } while (0)

#define STAGE_B8(S, H, TT) do {                                               \
    GLD_LDS16(pB[H][0] + (TT) * 64,                                           \
              Bs + (S) * 16384 + ((H) * 32 + (wv >> 2) * 64 + (wv & 3) * 8) * 64); \
    GLD_LDS16(pB[H][1] + (TT) * 64,                                           \
              Bs + (S) * 16384 + ((H) * 32 + 128 + (wv >> 2) * 64 + (wv & 3) * 8) * 64); \
  } while (0)

#define RD_A8(S, MH) do {                                                     \
    _Pragma("unroll")                                                         \
    for (int mf = 0; mf < 4; ++mf) {                                          \
      const u16* p_ = As + (S) * 16384 + rdA + ((MH) * 64 + mf * 16) * 64;    \
      a[mf][0] = *(const bf16x8*)(p_ + pos0);                                 \
      a[mf][1] = *(const bf16x8*)(p_ + pos1);                                 \
    }                                                                         \
  } while (0)

#define RD_B8(S, NH) do {                                                     \
    _Pragma("unroll")                                                         \
    for (int nf = 0; nf < 2; ++nf) {                                          \
      const u16* p_ = Bs + (S) * 16384 + rdB + ((NH) * 32 + nf * 16) * 64;    \
      b[nf][0] = *(const bf16x8*)(p_ + pos0);                                 \
      b[nf][1] = *(const bf16x8*)(p_ + pos1);                                 \
    }                                                                         \
  } while (0)

#define MFMA_Q8(MH, NH) do {                                                  \
    _Pragma("unroll")                                                         \
    for (int ks = 0; ks < 2; ++ks)                                            \
      _Pragma("unroll")                                                       \
      for (int mf = 0; mf < 4; ++mf)                                          \
        _Pragma("unroll")                                                     \
        for (int nf = 0; nf < 2; ++nf)                                        \
          acc[(MH) * 4 + mf][(NH) * 2 + nf] =                                 \
              __builtin_amdgcn_mfma_f32_16x16x32_bf16(                        \
                  a[mf][ks], b[nf][ks], acc[(MH) * 4 + mf][(NH) * 2 + nf],    \
                  0, 0, 0);                                                   \
  } while (0)

#define GROUP8(S, T, EN1, EN2, WAITST) do {                                   \
    RD_A8(S, 0); RD_B8(S, 0);                                                 \
    if (EN1) STAGE_B8((S) ^ 1, 0, (T) + 1);                                   \
    BARR8; WAITL8;                                                            \
    __builtin_amdgcn_s_setprio(1); MFMA_Q8(0, 0);                             \
    __builtin_amdgcn_s_setprio(0); BARR8;                                     \
    RD_B8(S, 1);                                                              \
    if (EN2) STAGE_A8(S, 0, (T) + 2);                                         \
    BARR8; WAITL8;                                                            \
    __builtin_amdgcn_s_setprio(1); MFMA_Q8(0, 1);                             \
    __builtin_amdgcn_s_setprio(0); BARR8;                                     \
    RD_A8(S, 1);                                                              \
    if (EN2) STAGE_B8(S, 1, (T) + 2);                                         \
    BARR8; WAITL8;                                                            \
    __builtin_amdgcn_s_setprio(1); MFMA_Q8(1, 1);                             \
    __builtin_amdgcn_s_setprio(0); BARR8;                                     \
    RD_B8(S, 0);                                                              \
    if (EN2) STAGE_A8(S, 1, (T) + 2);                                         \
    BARR8; WAITL8;                                                            \
    __builtin_amdgcn_s_setprio(1); MFMA_Q8(1, 0);                             \
    __builtin_amdgcn_s_setprio(0); WAITST; BARR8;                             \
  } while (0)

template <int NT>
__global__ __launch_bounds__(512)
void gemm8s(const u16* __restrict__ A, int lda, long long sA,
            const u16* __restrict__ B, int ldb, long long sB,
            u16* __restrict__ C, int ldc, long long sC,
            float* __restrict__ rsum, float scale) {
  __shared__ __align__(16) u16 As[2 * 256 * 64];
  __shared__ __align__(16) u16 Bs[2 * 256 * 64];

  const int lane = threadIdx.x & 63;
  const int wv   = threadIdx.x >> 6;    // 0..7
  const int wm   = wv >> 2;             // 0..1
  const int wn   = wv & 3;              // 0..3
  const int l15  = lane & 15;
  const int hi4  = lane >> 4;           // 0..3
  const int rx7  = lane & 7;
  const int srow = lane >> 3;           // 0..7
  const int scem = ((lane & 7) ^ srow) * 8;

  // bijective XCD swizzle (nwg % 8 == 0)
  const int nx = gridDim.x;
  const int flat = blockIdx.y * nx + blockIdx.x;
  const int nwg = nx * gridDim.y;
  const int cpx = nwg >> 3;
  const int swz = (flat & 7) * cpx + (flat >> 3);
  const int bx = swz % nx, by = swz / nx;

  const u16* Ab = A + (size_t)blockIdx.z * sA + (size_t)by * 256 * lda;
  const u16* Bb = B + (size_t)blockIdx.z * sB + (size_t)bx * 256 * ldb;

  const u16* pA[2][2];
  const u16* pB[2][2];
  #pragma unroll
  for (int h = 0; h < 2; ++h)
    #pragma unroll
    for (int r = 0; r < 2; ++r) {
      pA[h][r] = Ab + (size_t)(h * 64 + r * 128 + wv * 8 + srow) * lda + scem;
      pB[h][r] = Bb + (size_t)(h * 32 + r * 128 + (wv >> 2) * 64 +
                               (wv & 3) * 8 + srow) * ldb + scem;
    }

  const int rdA = (wm * 128 + l15) * 64;
  const int rdB = (wn * 64 + l15) * 64;
  const int pos0 = (hi4 ^ rx7) * 8;
  const int pos1 = ((4 + hi4) ^ rx7) * 8;

  f32x4 acc[8][4];
  #pragma unroll
  for (int i = 0; i < 8; ++i)
    #pragma unroll
    for (int j = 0; j < 4; ++j) acc[i][j] = (f32x4)0.0f;

  bf16x8 a[4][2], b[2][2];

  STAGE_A8(0, 0, 0); STAGE_B8(0, 1, 0); STAGE_A8(0, 1, 0); STAGE_B8(0, 0, 0);
  VMW(4);
  STAGE_A8(1, 0, 1); STAGE_B8(1, 1, 1); STAGE_A8(1, 1, 1);
  VMW(6);
  BARR8;

  #pragma unroll 1
  for (int i = 0; i < NT / 2 - 1; ++i) {
    const int t0 = 2 * i;
    GROUP8(0, t0,     1, 1, VMW(6));
    GROUP8(1, t0 + 1, 1, 1, VMW(6));
  }
  GROUP8(0, NT - 2, 1, 0, VMW(0));
  GROUP8(1, NT - 1, 0, 0, (void)0);

  // epilogue: P = bf16(exp(v-8)), rsum[m] += sum of rounded row values
  const int m0 = by * 256 + wm * 128;
  const int n0 = bx * 256 + wn * 64;
  u16* Cb = C + (size_t)blockIdx.z * sC;
  float* rsz = rsum + blockIdx.z * 2048;
  #pragma unroll
  for (int fm = 0; fm < 8; ++fm) {
    const int mb = m0 + (fm >> 2) * 64 + (fm & 3) * 16 + hi4 * 4;
    #pragma unroll
    for (int e = 0; e < 4; ++e) {
      const int m = mb + e;
      float local = 0.f;
      #pragma unroll
      for (int fn = 0; fn < 4; ++fn) {
        const int n = n0 + (fn >> 1) * 32 + (fn & 1) * 16 + l15;
        float ex = exp2f((acc[fm][fn][e] * scale - 8.0f) * 1.44269504f);
        u16 pb = f2bf(ex);
        Cb[(size_t)m * ldc + n] = pb;
        local += bf2f(pb);
      }
      #pragma unroll
      for (int mk = 1; mk < 16; mk <<= 1) local += __shfl_xor(local, mk);
      if (l15 == 0) atomicAdd(&rsz[m], local);
    }
  }
}

// ---------------- PV GEMM: m97-style 512-thread, normalize by rsum --------
// out[m][n] = (sum_k P[m][k]*vT[n][k]) / rsum[m]. Grid (8,16,4) = 512 blocks.

__global__ __launch_bounds__(512)
void gemm_bt8(const u16* __restrict__ A, int lda, long long sA,
              const u16* __restrict__ B, int ldb, long long sB,
              float* __restrict__ C, int ldc, long long sC,
              int K, const float* __restrict__ rsum) {
  __shared__ u16 As[128 * 64];
  __shared__ u16 Bs[128 * 64];
  const int lane = threadIdx.x & 63;
  const int wv = threadIdx.x >> 6;          // 0..7

  const u16* Ab = A + (size_t)blockIdx.z * sA + (size_t)blockIdx.y * 128 * lda;
  const u16* Bb = B + (size_t)blockIdx.z * sB + (size_t)blockIdx.x * 128 * ldb;

  const int srow = lane >> 3;
  const int scol = ((lane & 7) ^ (lane >> 3)) * 8;
  const int r32 = lane & 31;
  const int half = lane >> 5;
  const int rx = lane & 7;
  const int wm = (wv >> 2) * 64;
  const int wn = (wv & 3) * 32;

  f32x16 acc[2];
  acc[0] = (f32x16)0.0f; acc[1] = (f32x16)0.0f;

  for (int k0 = 0; k0 < K; k0 += 64) {
    #pragma unroll
    for (int i = 0; i < 2; ++i) {
      int r = wv * 16 + i * 8;
      GLD_LDS16(Ab + (size_t)(r + srow) * lda + k0 + scol, As + r * 64);
      GLD_LDS16(Bb + (size_t)(r + srow) * ldb + k0 + scol, Bs + r * 64);
    }
    __syncthreads();

    bf16x8 af[2][4], bfr[4];
    #pragma unroll
    for (int t = 0; t < 4; ++t) {
      int pc = ((t * 2 + half) ^ rx) * 8;
      af[0][t] = *(const bf16x8*)(As + (wm + r32) * 64 + pc);
      af[1][t] = *(const bf16x8*)(As + (wm + 32 + r32) * 64 + pc);
      bfr[t]   = *(const bf16x8*)(Bs + (wn + r32) * 64 + pc);
    }
    #pragma unroll
    for (int i = 0; i < 2; ++i)
      #pragma unroll
      for (int t = 0; t < 4; ++t)
        acc[i] = __builtin_amdgcn_mfma_f32_32x32x16_bf16(
            af[i][t], bfr[t], acc[i], 0, 0, 0);
    __syncthreads();
  }

  const int ccol = blockIdx.x * 128 + wn + r32;
  const int crow0 = blockIdx.y * 128 + wm + 4 * half;
  float* Cf = C + (size_t)blockIdx.z * sC;
  const float* rsz = rsum + blockIdx.z * 2048;
  #pragma unroll
  for (int i = 0; i < 2; ++i)
    #pragma unroll
    for (int e = 0; e < 16; ++e) {
      int m = crow0 + i * 32 + (e & 3) + 8 * (e >> 2);
      Cf[(size_t)m * ldc + ccol] = acc[i][e] / rsz[m];
    }
}

// ---------------- launch ----------------

extern "C" void kernel_launch(void* const* d_in, const int* in_sizes, int n_in,
                              void* d_out, int out_size, void* d_ws, size_t ws_size,
                              hipStream_t stream) {
  const float* x  = (const float*)d_in[0];
  const float* Wk = (const float*)d_in[1];
  const float* bk = (const float*)d_in[2];
  const float* Wq = (const float*)d_in[3];
  const float* bq = (const float*)d_in[4];
  const float* Wv = (const float*)d_in[5];
  const float* bv = (const float*)d_in[6];
  float* out = (float*)d_out;

  char* ws = (char*)d_ws;
  u16*   xb   = (u16*)(ws + 0);
  u16*   wt   = (u16*)(ws + 16777216);
  float* bc   = (float*)(ws + 23068672);
  u16*   qk   = (u16*)(ws + 23080960);
  u16*   vT   = (u16*)(ws + 56635392);
  u16*   P    = (u16*)(ws + 73412608);
  float* rsum = (float*)(ws + 106967040);
  (void)in_sizes; (void)n_in; (void)out_size; (void)ws_size;

  // 1. fused prep: x->bf16 | W^T->bf16 (64x64 tiles) | bias | rsum = 0
  prep_all<<<4880, 256, 0, stream>>>(x, Wq, Wk, Wv, bq, bk, bv, xb, wt, bc,
                                     rsum);

  // 2. fused QKV projection: q/k cols -> qk (ldc 2048), v cols -> vT
  //    (m97 128^2, grid 24x64 = 1536 blocks, XCD swizzled)
  gemm_qkv<<<dim3(24, 64, 1), 256, 0, stream>>>(
      xb, 1024, wt, 1024, qk, 2048, bc, 1024, vT);

  // 3. scores -> P = exp(qk^T/32 - 8) bf16, rsum accumulated (8-phase 256^2)
  gemm8s<16><<<dim3(8, 8, 4), 512, 0, stream>>>(
      qk, 2048, 2048LL * 2048, qk + 1024, 2048, 2048LL * 2048,
      P, 2048, 2048LL * 2048, rsum, 0.03125f);

  // 4. out = (P @ V) / rsum  (m97-style 512-thread, 512 blocks)
  gemm_bt8<<<dim3(8, 16, 4), 512, 0, stream>>>(
      P, 2048, 2048LL * 2048, vT, 2048, 1024LL * 2048,
      out, 1024, 2048LL * 1024, 2048, rsum);
}